// Round 4
// baseline (301.567 us; speedup 1.0000x reference)
//
#include <hip/hip_runtime.h>

#define ALPHA_MIN 0.8187307530779818f  // exp(-1/5)
#define ALPHA_MAX 0.9607894391523232f  // exp(-1/25)

typedef _Float16 f16;
typedef _Float16 f16x4 __attribute__((ext_vector_type(4)));
typedef _Float16 f16x8 __attribute__((ext_vector_type(8)));
typedef float f32x16 __attribute__((ext_vector_type(16)));

// Fixed problem shape
#define BB_ 32
#define TT_ 2048
#define KK_ 256
#define HH_ 512
#define TC_ 64               // timesteps per chunk
#define KH_ 128              // k-half (two halves of K=256)
#define CPB_ 16              // chunks per block (time axis split in half)

// Barrier WITHOUT vmcnt drain: waits LDS ops only, leaves global loads in
// flight across the barrier. imm 0xC07F = vmcnt(63) expcnt(7) lgkmcnt(0).
__device__ __forceinline__ void barrier_lds() {
    __builtin_amdgcn_s_waitcnt(0xC07F);
    __builtin_amdgcn_s_barrier();
}

// ============================ kernel 1: GEMM ================================
// DECOUPLED from the scan (R3 post-mortem: three fused structures all pinned
// at ~11 us/chunk with ~75% of each phase unexplained -> stop polishing the
// coupled schedule, isolate the GEMM machinery).
// Computes Wx (fp16-split, numerically exact vs fp32 GEMM) -> out (fp32).
// grid 512 = (half<<8)|(nt<<5)|b  -> XCD = b%8 (the 16 blocks of batch b
// share X[b] in one XCD L2); 2 blocks/CU (LDS 64 KB) so a second block's
// waves fill coupling stalls.
// block 512 = 8 waves: 4 MFMA (one 32x32 tile each) + 4 stagers (depth-2
// register prefetch pA/pB, fp32->f16 hi/lo split, swizzled LDS write).
// Epilogue: direct global stores (fire-and-forget; no consumer coupling).
// fp16-split: C = Ah*Bh + 2^-11*(Ah*Bl + Al*Bh); B-panel in registers.
__global__ __launch_bounds__(512, 1) void wx_gemm(
    const float* __restrict__ X,      // (B,T,K)
    const float* __restrict__ W,      // (H,K)
    float* __restrict__ out)          // (B,T,H)  <- Wx
{
    __shared__ f16 Ah[2][TC_ * KH_];         // 2 x 16 KB (swizzled 8-f16 groups)
    __shared__ f16 Al[2][TC_ * KH_];         // 2 x 16 KB
    // total LDS = 64 KB -> 2 blocks/CU

    const int b    = blockIdx.x & 31;
    const int nt   = (blockIdx.x >> 5) & 7;
    const int half = blockIdx.x >> 8;
    const int n0   = nt * 64;
    const int c0   = half * CPB_;
    const int c1   = c0 + CPB_;

    const int tid  = threadIdx.x;
    const int wv   = tid >> 6;               // 0..7
    const int lane = tid & 63;
    const int fm   = lane & 31;
    const int fq   = lane >> 5;

    if (wv < 4) {
        // ========================= MFMA waves ==============================
        const int mh = wv >> 1;              // t-half of chunk tile
        const int nh = wv & 1;               // n-half of panel

        // ---- B prologue: W[n0+nh*32+fm][:] -> hi/lo f16 register frags ----
        f16x8 bh[16], bl[16];
        {
            const float* wp = W + (size_t)(n0 + nh * 32 + fm) * KK_ + fq * 8;
#pragma unroll
            for (int ks = 0; ks < 16; ++ks) {
                float4 v0 = *(const float4*)(wp + ks * 16);
                float4 v1 = *(const float4*)(wp + ks * 16 + 4);
                float v[8] = {v0.x, v0.y, v0.z, v0.w, v1.x, v1.y, v1.z, v1.w};
                f16x8 h, l;
#pragma unroll
                for (int j = 0; j < 8; ++j) {
                    const f16 hj = (f16)v[j];
                    h[j] = hj;
                    l[j] = (f16)((v[j] - (float)hj) * 2048.0f);
                }
                bh[ks] = h; bl[ks] = l;
            }
        }

        f32x16 accH, accLa, accLb;
#pragma unroll
        for (int e = 0; e < 16; ++e) { accH[e] = 0.0f; accLa[e] = 0.0f; accLb[e] = 0.0f; }

        const int row = mh * 32 + fm;
        const int r15 = row & 15;

        auto compute_half = [&](int hf) {
            __builtin_amdgcn_s_setprio(1);
#pragma unroll
            for (int ks = 0; ks < 8; ++ks) {
                const int addr = row * KH_ + (((ks * 2 + fq) ^ r15) * 8);
                const f16x8 ah = *(const f16x8*)&Ah[hf][addr];
                const f16x8 al = *(const f16x8*)&Al[hf][addr];
                const int ksg = hf * 8 + ks;
                accH  = __builtin_amdgcn_mfma_f32_32x32x16_f16(ah, bh[ksg], accH,  0, 0, 0);
                accLa = __builtin_amdgcn_mfma_f32_32x32x16_f16(ah, bl[ksg], accLa, 0, 0, 0);
                accLb = __builtin_amdgcn_mfma_f32_32x32x16_f16(al, bh[ksg], accLb, 0, 0, 0);
            }
            __builtin_amdgcn_s_setprio(0);
        };

        barrier_lds();                            // prologue barrier
        for (int c = c0; c < c1; ++c) {
            // phase A: MFMA on (c, kh0) from buf0; stagers fill buf1
            compute_half(0);
            barrier_lds();
            // phase B: MFMA on (c, kh1) from buf1 + direct global epilogue
            compute_half(1);
            {
                float* op = out + ((size_t)b * TT_ + (size_t)c * TC_) * HH_ + n0;
                const int colw = nh * 32 + fm;
#pragma unroll
                for (int r = 0; r < 16; ++r) {
                    const int roww = mh * 32 + (r & 3) + 8 * (r >> 2) + 4 * fq;
                    op[(size_t)roww * HH_ + colw] =
                        accH[r] + (accLa[r] + accLb[r]) * (1.0f / 2048.0f);
                    accH[r] = 0.0f; accLa[r] = 0.0f; accLb[r] = 0.0f;
                }
            }
            barrier_lds();
        }
    } else {
        // ========================= stager waves ============================
        // wave u owns rows u*16 .. u*16+15 of the 64-row chunk tile.
        // instr j covers rows u*16 + j*2 + {0,1}; 32 lanes x 16 B = one
        // contiguous 512 B k-half row -> coalesced.
        // Depth-2 prefetch: pA = even half-steps, pB = odd; static reg
        // indexing only.
        const int u      = wv - 4;
        const int srow_j = u * 16 + (lane >> 5);    // + j*2
        const int f4i    = lane & 31;
        const int g      = f4i >> 1;                // 8-f16 group 0..15
        const int sub    = f4i & 1;

        float4 pA[8], pB[8];

        auto issueA = [&](int hs) {                 // even half-step -> pA
            const int c = hs >> 1, kh = hs & 1;
            const float* base = X + ((size_t)b * TT_ + (size_t)c * TC_) * KK_ + kh * KH_ + f4i * 4;
#pragma unroll
            for (int j = 0; j < 8; ++j)
                pA[j] = *(const float4*)(base + (size_t)(srow_j + j * 2) * KK_);
        };
        auto issueB = [&](int hs) {                 // odd half-step -> pB
            const int c = hs >> 1, kh = hs & 1;
            const float* base = X + ((size_t)b * TT_ + (size_t)c * TC_) * KK_ + kh * KH_ + f4i * 4;
#pragma unroll
            for (int j = 0; j < 8; ++j)
                pB[j] = *(const float4*)(base + (size_t)(srow_j + j * 2) * KK_);
        };
        auto cvtA = [&](int bufi) {                 // pA -> buf[bufi]
#pragma unroll
            for (int j = 0; j < 8; ++j) {
                const int rowa = srow_j + j * 2;
                const float v[4] = {pA[j].x, pA[j].y, pA[j].z, pA[j].w};
                f16x4 h, l;
#pragma unroll
                for (int e = 0; e < 4; ++e) {
                    const f16 he = (f16)v[e];
                    h[e] = he;
                    l[e] = (f16)((v[e] - (float)he) * 2048.0f);
                }
                const int addr = rowa * KH_ + ((g ^ (rowa & 15)) * 8) + sub * 4;
                *(f16x4*)&Ah[bufi][addr] = h;
                *(f16x4*)&Al[bufi][addr] = l;
            }
        };
        auto cvtB = [&](int bufi) {                 // pB -> buf[bufi]
#pragma unroll
            for (int j = 0; j < 8; ++j) {
                const int rowa = srow_j + j * 2;
                const float v[4] = {pB[j].x, pB[j].y, pB[j].z, pB[j].w};
                f16x4 h, l;
#pragma unroll
                for (int e = 0; e < 4; ++e) {
                    const f16 he = (f16)v[e];
                    h[e] = he;
                    l[e] = (f16)((v[e] - (float)he) * 2048.0f);
                }
                const int addr = rowa * KH_ + ((g ^ (rowa & 15)) * 8) + sub * 4;
                *(f16x4*)&Ah[bufi][addr] = h;
                *(f16x4*)&Al[bufi][addr] = l;
            }
        };

        // prologue: h(2c0) -> buf0; leave h(2c0+1), h(2c0+2) in flight
        issueA(2 * c0);
        issueB(2 * c0 + 1);
        cvtA(0);
        issueA(2 * c0 + 2);
        barrier_lds();                // prologue barrier

        for (int c = c0; c < c1; ++c) {
            // phase A: buf1 <- h(2c+1) from pB; issue h(2c+3) -> pB
            cvtB(1);
            if (c + 1 < c1) issueB(2 * c + 3);
            barrier_lds();
            // phase B: buf0 <- h(2c+2) from pA; issue h(2c+4) -> pA
            if (c + 1 < c1) cvtA(0);
            if (c + 2 < c1) issueA(2 * c + 4);
            barrier_lds();
        }
    }
}

// ============================ kernel 2: scan ================================
// 16384 independent (b,h) chains, one thread each, in-place on out:
// reads Wx (fp32, just written -> LLC-resident), writes spike 0/1.
// 256 blocks x 64 threads = 1 wave/CU across all 256 CUs.
// Depth-32 A/B register prefetch: 32 strided loads issued, then 32 serial
// LIF steps (~450 cyc) cover the LLC latency of the other buffer.
__global__ __launch_bounds__(64) void lif_scan_opt(
    float* __restrict__ buf,          // (B,T,H): in Wx, out spikes
    const float* __restrict__ alpha,
    const float* __restrict__ u0,
    const float* __restrict__ s0)
{
    const int chain = blockIdx.x * 64 + threadIdx.x;   // 0..16383
    const int h = chain & (HH_ - 1);
    const int b = chain >> 9;
    float a = alpha[h];
    a = fminf(fmaxf(a, ALPHA_MIN), ALPHA_MAX);
    const float bbv = 1.0f - a;
    float u = u0[chain];
    float s = s0[chain];
    float* base = buf + (size_t)b * TT_ * HH_ + h;

    float wA[32], wB[32];

    auto loadA = [&](int t0) {
#pragma unroll
        for (int i = 0; i < 32; ++i) wA[i] = base[(size_t)(t0 + i) * HH_];
    };
    auto loadB = [&](int t0) {
#pragma unroll
        for (int i = 0; i < 32; ++i) wB[i] = base[(size_t)(t0 + i) * HH_];
    };
    auto stepA = [&](int t0) {
#pragma unroll
        for (int i = 0; i < 32; ++i) {
            u = fmaf(a, u - s, bbv * wA[i]);
            s = (u > 1.0f) ? 1.0f : 0.0f;
            base[(size_t)(t0 + i) * HH_] = s;
        }
    };
    auto stepB = [&](int t0) {
#pragma unroll
        for (int i = 0; i < 32; ++i) {
            u = fmaf(a, u - s, bbv * wB[i]);
            s = (u > 1.0f) ? 1.0f : 0.0f;
            base[(size_t)(t0 + i) * HH_] = s;
        }
    };

    loadA(0);
    for (int t0 = 0; t0 < TT_; t0 += 64) {
        loadB(t0 + 32);               // prefetch next 32 while stepping A
        stepA(t0);
        if (t0 + 64 < TT_) loadA(t0 + 64);
        stepB(t0 + 32);
    }
}

// =================== generic fallback (non-reference shapes) ================
__global__ void gemm_naive(const float* __restrict__ X, const float* __restrict__ W,
                           float* __restrict__ C, int M, int N, int K)
{
    const int idx = blockIdx.x * 256 + threadIdx.x;
    if (idx >= M * N) return;
    const int m = idx / N, n = idx % N;
    float acc = 0.0f;
    for (int k = 0; k < K; ++k) acc = fmaf(X[(size_t)m * K + k], W[(size_t)n * K + k], acc);
    C[idx] = acc;
}

__global__ __launch_bounds__(64) void lif_scan_inplace(
    float* __restrict__ buf, const float* __restrict__ alpha,
    const float* __restrict__ u0, const float* __restrict__ s0, int T, int H)
{
    const int chain = blockIdx.x * 64 + threadIdx.x;
    const int h = chain % H;
    const int b = chain / H;
    float a = alpha[h];
    a = fminf(fmaxf(a, ALPHA_MIN), ALPHA_MAX);
    const float bb = 1.0f - a;
    float u = u0[chain], s = s0[chain];
    float* base = buf + (size_t)b * T * H + h;
    for (int t = 0; t < T; ++t) {
        u = fmaf(a, u - s, bb * base[(size_t)t * H]);
        s = (u > 1.0f) ? 1.0f : 0.0f;
        base[(size_t)t * H] = s;
    }
}

// ---------------- launch ----------------------------------------------------
extern "C" void kernel_launch(void* const* d_in, const int* in_sizes, int n_in,
                              void* d_out, int out_size, void* d_ws, size_t ws_size,
                              hipStream_t stream) {
    const float* x     = (const float*)d_in[0];
    const float* W     = (const float*)d_in[1];
    const float* alpha = (const float*)d_in[2];
    const float* u0    = (const float*)d_in[3];
    const float* s0    = (const float*)d_in[4];
    float* out = (float*)d_out;

    const int H = in_sizes[2];
    const int I = in_sizes[1] / H;
    const int B = in_sizes[3] / H;
    const int T = in_sizes[0] / (B * I);

    if (B == BB_ && T == TT_ && I == KK_ && H == HH_) {
        wx_gemm<<<512, 512, 0, stream>>>(x, W, out);
        lif_scan_opt<<<256, 64, 0, stream>>>(out, alpha, u0, s0);
    } else {
        const int M = B * T;
        gemm_naive<<<(M * H + 255) / 256, 256, 0, stream>>>(x, W, out, M, H, I);
        lif_scan_inplace<<<(B * H + 63) / 64, 64, 0, stream>>>(out, alpha, u0, s0, T, H);
    }
}